// Round 1
// baseline (301.407 us; speedup 1.0000x reference)
//
#include <hip/hip_runtime.h>

typedef _Float16 f16;
typedef _Float16 half8 __attribute__((ext_vector_type(8)));
typedef _Float16 half4 __attribute__((ext_vector_type(4)));
typedef float f32x4 __attribute__((ext_vector_type(4)));

#define BTOT 65536

// ---------------- workspace layout ----------------
// flat : f16 [BTOT][768]            @ 0
// wg   : f32 fused per-group blocks @ FLAT_BYTES
//        per group: [WtA D*D][WtB 64*D][u D][w D][co 64][c 1], padded to %4 floats
// wiT  : f16 [256][768]             @ WIT_OFF
static const size_t FLAT_BYTES = (size_t)BTOT * 768 * 2;   // 100,663,296
#define WG_G0 0
#define WG_G1 24900
#define WG_G2 33288
#define WG_G3 58188
#define WG_FLOATS 66576

// =============== weight-fusion precompute ===============
// one thread per output element; each is a length-D dot (weights are L2-resident)
__global__ __launch_bounds__(256) void pk_group(
    const float* __restrict__ wq0, const float* __restrict__ bq0, const float* __restrict__ wo0, const float* __restrict__ bo0,
    const float* __restrict__ wq1, const float* __restrict__ bq1, const float* __restrict__ wo1, const float* __restrict__ bo1,
    const float* __restrict__ wq2, const float* __restrict__ bq2, const float* __restrict__ wo2, const float* __restrict__ bo2,
    const float* __restrict__ wq3, const float* __restrict__ bq3, const float* __restrict__ wo3, const float* __restrict__ bo3,
    float* __restrict__ wgAll)
{
    const int g = blockIdx.y;
    const float* wqkv; const float* bqkv; const float* wo; const float* bo; int D; int off;
    switch (g) {
        case 0:  wqkv = wq0; bqkv = bq0; wo = wo0; bo = bo0; D = 128; off = WG_G0; break;
        case 1:  wqkv = wq1; bqkv = bq1; wo = wo1; bo = bo1; D = 64;  off = WG_G1; break;
        case 2:  wqkv = wq2; bqkv = bq2; wo = wo2; bo = bo2; D = 128; off = WG_G2; break;
        default: wqkv = wq3; bqkv = bq3; wo = wo3; bo = bo3; D = 64;  off = WG_G3; break;
    }
    const int dd = D * D, s3 = 3 * D;
    const int total = dd + 64 * D + 2 * D + 64 + 1;
    const int o = blockIdx.x * 256 + threadIdx.x;
    if (o >= total) return;
    float* out = wgAll + off;
    if (o < dd) {                              // WtA[n][k] = (Wq WkT)[k][n]/sqrt(D)
        int n = o / D, k = o - n * D;
        const float* a = wqkv + (size_t)k * s3;        // Wq row k
        const float* b = wqkv + (size_t)n * s3 + D;    // Wk row n
        float s = 0.f;
        for (int m = 0; m < D; m += 4)
            s += a[m]*b[m] + a[m+1]*b[m+1] + a[m+2]*b[m+2] + a[m+3]*b[m+3];
        out[o] = s * rsqrtf((float)D);
    } else if (o < dd + 64 * D) {              // WtB[n][k] = (Wv wo)[k][n]
        int oo = o - dd; int n = oo / D, k = oo - n * D;
        const float* a = wqkv + (size_t)k * s3 + 2 * D;
        float s = 0.f;
        for (int m = 0; m < D; ++m) s += a[m] * wo[m * 64 + n];
        out[o] = s;
    } else if (o < dd + 64 * D + D) {          // u = Wq bk
        int i = o - dd - 64 * D;
        const float* a = wqkv + (size_t)i * s3;
        float s = 0.f;
        for (int m = 0; m < D; ++m) s += a[m] * bqkv[D + m];
        out[o] = s;
    } else if (o < dd + 64 * D + 2 * D) {      // w = Wk bq
        int i = o - dd - 64 * D - D;
        const float* a = wqkv + (size_t)i * s3 + D;
        float s = 0.f;
        for (int m = 0; m < D; ++m) s += a[m] * bqkv[m];
        out[o] = s;
    } else if (o < dd + 64 * D + 2 * D + 64) { // co = bv wo + bo
        int n = o - dd - 64 * D - 2 * D;
        float s = 0.f;
        for (int m = 0; m < D; ++m) s += bqkv[2 * D + m] * wo[m * 64 + n];
        out[o] = s + bo[n];
    } else {                                   // c = bq . bk
        float s = 0.f;
        for (int m = 0; m < D; ++m) s += bqkv[m] * bqkv[D + m];
        out[o] = s;
    }
}

// wiT[n][k] = (f16) wi[k][n]  (wi is [768][256])
__global__ __launch_bounds__(256) void pk_wit(const float* __restrict__ wi, f16* __restrict__ wiT)
{
    int o = blockIdx.x * 256 + threadIdx.x;    // 196608 outputs
    int n = o / 768, k = o - n * 768;
    wiT[o] = (f16)wi[k * 256 + n];
}

// =============== kernel 1: fused group attention ===============
// grid = (1024, 2); block = 512 (8 waves as 4x2 wave grid); BT=64 batches -> M=192 rows
template<int D>
__global__ __launch_bounds__(512) void k1_attn(
    const float* __restrict__ words, const float* __restrict__ wgAll, f16* __restrict__ flat)
{
    constexpr int KST = D / 32;       // mfma K-steps
    constexpr int CPW = D / 32;       // col-tiles per wave, phase A ((D/16)/2)
    constexpr int XP  = D + 8;        // padded LDS row (2-way bank alias only)

    const int y = blockIdx.y;
    int start, wgoff, fbase;
    if (D == 128) { start = 192 * y;       wgoff = WG_G0 + (WG_G2 - WG_G0) * y; fbase = 384 * y; }
    else          { start = 128 + 192 * y; wgoff = WG_G1 + (WG_G3 - WG_G1) * y; fbase = 192 + 384 * y; }
    const float* wg = wgAll + wgoff;
    const int b0 = blockIdx.x * 64;

    __shared__ f16 Xs[192][XP];
    __shared__ f16 Ws[D][XP];         // phase A: A^T (D rows); phase B: Wvo^T (64 rows)
    __shared__ f16 Zs[192][XP];
    __shared__ float Sc[64 * 9];
    __shared__ float xuw[2 * 192];
    __shared__ float ubuf[D], wbuf2[D], cobuf[64], cbuf[1];

    const int t = threadIdx.x;

    // stage X tile (fp32 -> f16)
    for (int u = t; u < 192 * (D / 4); u += 512) {
        int r = u / (D / 4), c4 = u - r * (D / 4);
        float4 v = *(const float4*)&words[(size_t)(b0 * 3 + r) * 384 + start + c4 * 4];
        half4 h; h[0] = (f16)v.x; h[1] = (f16)v.y; h[2] = (f16)v.z; h[3] = (f16)v.w;
        *(half4*)&Xs[r][c4 * 4] = h;
    }
    // stage WtA
    for (int u = t; u < D * (D / 4); u += 512) {
        int r = u / (D / 4), c4 = u - r * (D / 4);
        float4 v = *(const float4*)&wg[r * D + c4 * 4];
        half4 h; h[0] = (f16)v.x; h[1] = (f16)v.y; h[2] = (f16)v.z; h[3] = (f16)v.w;
        *(half4*)&Ws[r][c4 * 4] = h;
    }
    // stage bias vectors
    if (t < D) ubuf[t] = wg[D * D + 64 * D + t];
    else if (t < 2 * D) wbuf2[t - D] = wg[D * D + 64 * D + D + (t - D)];
    else if (t < 2 * D + 64) cobuf[t - 2 * D] = wg[D * D + 64 * D + 2 * D + (t - 2 * D)];
    else if (t == 2 * D + 64) cbuf[0] = wg[D * D + 64 * D + 2 * D + 64];
    __syncthreads();

    const int wv = t >> 6, lane = t & 63;
    const int wr = wv >> 1, wc = wv & 1;       // 4x2 wave grid
    const int lrow = lane & 15, lk = lane >> 4;

    // ---- phase A: Z = X @ A ----
    f32x4 acc[3][CPW];
    #pragma unroll
    for (int i = 0; i < 3; ++i)
        #pragma unroll
        for (int j = 0; j < CPW; ++j) acc[i][j] = f32x4{0.f, 0.f, 0.f, 0.f};
    #pragma unroll
    for (int kk = 0; kk < KST; ++kk) {
        half8 a[3];
        #pragma unroll
        for (int rt = 0; rt < 3; ++rt)
            a[rt] = *(const half8*)&Xs[wr * 48 + rt * 16 + lrow][kk * 32 + lk * 8];
        #pragma unroll
        for (int ct = 0; ct < CPW; ++ct) {
            half8 b = *(const half8*)&Ws[wc * (CPW * 16) + ct * 16 + lrow][kk * 32 + lk * 8];
            #pragma unroll
            for (int rt = 0; rt < 3; ++rt)
                acc[rt][ct] = __builtin_amdgcn_mfma_f32_16x16x32_f16(a[rt], b, acc[rt][ct], 0, 0, 0);
        }
    }
    #pragma unroll
    for (int rt = 0; rt < 3; ++rt)
        #pragma unroll
        for (int ct = 0; ct < CPW; ++ct)
            #pragma unroll
            for (int r = 0; r < 4; ++r)
                Zs[wr * 48 + rt * 16 + lk * 4 + r][wc * (CPW * 16) + ct * 16 + lrow] = (f16)acc[rt][ct][r];
    __syncthreads();

    // stage WtB (overwrites Ws rows 0..63) + per-row bias dots
    for (int u = t; u < 64 * (D / 4); u += 512) {
        int r = u / (D / 4), c4 = u - r * (D / 4);
        float4 v = *(const float4*)&wg[D * D + r * D + c4 * 4];
        half4 h; h[0] = (f16)v.x; h[1] = (f16)v.y; h[2] = (f16)v.z; h[3] = (f16)v.w;
        *(half4*)&Ws[r][c4 * 4] = h;
    }
    for (int it = t; it < 2 * 192; it += 512) {
        int r = it >> 1, which = it & 1;
        const float* bv = which ? wbuf2 : ubuf;
        float s = 0.f;
        for (int k = 0; k < D; k += 8) {
            half8 x = *(const half8*)&Xs[r][k];
            #pragma unroll
            for (int j = 0; j < 8; ++j) s += (float)x[j] * bv[k + j];
        }
        xuw[it] = s;
    }
    __syncthreads();

    // ---- scores: s[w1][w2] = Z[r1] . X[r2] + xu[r1] + xw[r2] + c ----
    for (int it = t; it < 576; it += 512) {
        int bb = it / 9, p = it - bb * 9, w1 = p / 3, w2 = p - w1 * 3;
        int r1 = bb * 3 + w1, r2 = bb * 3 + w2;
        float s = 0.f;
        for (int k = 0; k < D; k += 8) {
            half8 z = *(const half8*)&Zs[r1][k];
            half8 x = *(const half8*)&Xs[r2][k];
            #pragma unroll
            for (int j = 0; j < 8; ++j) s += (float)z[j] * (float)x[j];
        }
        Sc[it] = s + xuw[2 * r1 + 0] + xuw[2 * r2 + 1] + cbuf[0];
    }
    __syncthreads();
    // softmax over w2 (3 wide)
    if (t < 192) {
        int bb = t / 3, w1 = t - bb * 3;
        float* sp = &Sc[bb * 9 + w1 * 3];
        float m = fmaxf(sp[0], fmaxf(sp[1], sp[2]));
        float e0 = __expf(sp[0] - m), e1 = __expf(sp[1] - m), e2 = __expf(sp[2] - m);
        float inv = 1.0f / (e0 + e1 + e2);
        sp[0] = e0 * inv; sp[1] = e1 * inv; sp[2] = e2 * inv;
    }
    __syncthreads();

    // ---- phase B: Z2 = X @ Wvo (cols 0..63 of Zs) ----
    f32x4 acc2[3][2];
    #pragma unroll
    for (int i = 0; i < 3; ++i) { acc2[i][0] = f32x4{0.f,0.f,0.f,0.f}; acc2[i][1] = f32x4{0.f,0.f,0.f,0.f}; }
    #pragma unroll
    for (int kk = 0; kk < KST; ++kk) {
        half8 a[3];
        #pragma unroll
        for (int rt = 0; rt < 3; ++rt)
            a[rt] = *(const half8*)&Xs[wr * 48 + rt * 16 + lrow][kk * 32 + lk * 8];
        #pragma unroll
        for (int ct = 0; ct < 2; ++ct) {
            half8 b = *(const half8*)&Ws[wc * 32 + ct * 16 + lrow][kk * 32 + lk * 8];
            #pragma unroll
            for (int rt = 0; rt < 3; ++rt)
                acc2[rt][ct] = __builtin_amdgcn_mfma_f32_16x16x32_f16(a[rt], b, acc2[rt][ct], 0, 0, 0);
        }
    }
    #pragma unroll
    for (int rt = 0; rt < 3; ++rt)
        #pragma unroll
        for (int ct = 0; ct < 2; ++ct)
            #pragma unroll
            for (int r = 0; r < 4; ++r)
                Zs[wr * 48 + rt * 16 + lk * 4 + r][wc * 32 + ct * 16 + lrow] = (f16)acc2[rt][ct][r];
    __syncthreads();

    // ---- out = P @ Z2 + co, relu, -> flat ----
    for (int i = t; i < 64 * 24; i += 512) {
        int bb = i / 24, rem = i - bb * 24, w1 = rem >> 3, c8 = rem & 7;
        float p0 = Sc[bb * 9 + w1 * 3 + 0];
        float p1 = Sc[bb * 9 + w1 * 3 + 1];
        float p2 = Sc[bb * 9 + w1 * 3 + 2];
        half8 z0 = *(const half8*)&Zs[bb * 3 + 0][c8 * 8];
        half8 z1 = *(const half8*)&Zs[bb * 3 + 1][c8 * 8];
        half8 z2 = *(const half8*)&Zs[bb * 3 + 2][c8 * 8];
        half8 o;
        #pragma unroll
        for (int j = 0; j < 8; ++j) {
            float v = p0 * (float)z0[j] + p1 * (float)z1[j] + p2 * (float)z2[j] + cobuf[c8 * 8 + j];
            o[j] = (f16)fmaxf(v, 0.f);
        }
        *(half8*)&flat[(size_t)(b0 + bb) * 768 + fbase + w1 * 64 + c8 * 8] = o;
    }
}

// =============== kernel 2: MLP (flat @ wi -> relu -> @ wout) ===============
// grid = 512; block = 512 (8 waves, 4x2); 128 rows x 256 cols per block, K=768 in 12 chunks
__global__ __launch_bounds__(512) void k2_mlp(
    const f16* __restrict__ flat, const f16* __restrict__ wiT,
    const float* __restrict__ bi, const float* __restrict__ wout, const float* __restrict__ bout,
    float* __restrict__ out)
{
    __shared__ f16 Xs[128][72];
    __shared__ f16 Wsh[256][72];
    __shared__ float part[128][2];
    __shared__ float bi_l[256], wo_l[256];

    const int t = threadIdx.x;
    const int b0 = blockIdx.x * 128;
    if (t < 256) { bi_l[t] = bi[t]; wo_l[t] = wout[t]; }

    const int wv = t >> 6, lane = t & 63;
    const int wr = wv >> 1, wc = wv & 1;
    const int lrow = lane & 15, lk = lane >> 4;

    f32x4 acc[2][8];
    #pragma unroll
    for (int i = 0; i < 2; ++i)
        #pragma unroll
        for (int j = 0; j < 8; ++j) acc[i][j] = f32x4{0.f, 0.f, 0.f, 0.f};

    for (int kc = 0; kc < 12; ++kc) {
        __syncthreads();
        for (int u = t; u < 1024; u += 512) {
            int r = u >> 3, c8 = u & 7;
            *(half8*)&Xs[r][c8 * 8] = *(const half8*)&flat[(size_t)(b0 + r) * 768 + kc * 64 + c8 * 8];
        }
        for (int u = t; u < 2048; u += 512) {
            int n = u >> 3, c8 = u & 7;
            *(half8*)&Wsh[n][c8 * 8] = *(const half8*)&wiT[(size_t)n * 768 + kc * 64 + c8 * 8];
        }
        __syncthreads();
        #pragma unroll
        for (int ks = 0; ks < 2; ++ks) {
            half8 a0 = *(const half8*)&Xs[wr * 32 + lrow][ks * 32 + lk * 8];
            half8 a1 = *(const half8*)&Xs[wr * 32 + 16 + lrow][ks * 32 + lk * 8];
            #pragma unroll
            for (int ct = 0; ct < 8; ++ct) {
                half8 b = *(const half8*)&Wsh[wc * 128 + ct * 16 + lrow][ks * 32 + lk * 8];
                acc[0][ct] = __builtin_amdgcn_mfma_f32_16x16x32_f16(a0, b, acc[0][ct], 0, 0, 0);
                acc[1][ct] = __builtin_amdgcn_mfma_f32_16x16x32_f16(a1, b, acc[1][ct], 0, 0, 0);
            }
        }
    }

    float bo0 = bout[0];
    #pragma unroll
    for (int rt = 0; rt < 2; ++rt) {
        #pragma unroll
        for (int r = 0; r < 4; ++r) {
            float s = 0.f;
            #pragma unroll
            for (int ct = 0; ct < 8; ++ct) {
                int col = wc * 128 + ct * 16 + lrow;
                float v = acc[rt][ct][r] + bi_l[col];
                v = fmaxf(v, 0.f);
                s += v * wo_l[col];
            }
            s += __shfl_xor(s, 1, 64); s += __shfl_xor(s, 2, 64);
            s += __shfl_xor(s, 4, 64); s += __shfl_xor(s, 8, 64);
            if (lrow == 0) part[wr * 32 + rt * 16 + lk * 4 + r][wc] = s;
        }
    }
    __syncthreads();
    if (t < 128) out[b0 + t] = part[t][0] + part[t][1] + bo0;
}

// =============== host launcher ===============
extern "C" void kernel_launch(void* const* d_in, const int* in_sizes, int n_in,
                              void* d_out, int out_size, void* d_ws, size_t ws_size,
                              hipStream_t stream)
{
    const float* words = (const float*)d_in[0];
    const float* wq[4] = {(const float*)d_in[1], (const float*)d_in[5], (const float*)d_in[9],  (const float*)d_in[13]};
    const float* bq[4] = {(const float*)d_in[2], (const float*)d_in[6], (const float*)d_in[10], (const float*)d_in[14]};
    const float* wo[4] = {(const float*)d_in[3], (const float*)d_in[7], (const float*)d_in[11], (const float*)d_in[15]};
    const float* bo[4] = {(const float*)d_in[4], (const float*)d_in[8], (const float*)d_in[12], (const float*)d_in[16]};
    const float* wi   = (const float*)d_in[17];
    const float* bi   = (const float*)d_in[18];
    const float* wout = (const float*)d_in[19];
    const float* bout = (const float*)d_in[20];

    char* ws = (char*)d_ws;
    f16*   flat = (f16*)(ws);
    float* wg   = (float*)(ws + FLAT_BYTES);
    f16*   wiT  = (f16*)(ws + FLAT_BYTES + (size_t)WG_FLOATS * 4);

    pk_group<<<dim3(98, 4), 256, 0, stream>>>(
        wq[0], bq[0], wo[0], bo[0], wq[1], bq[1], wo[1], bo[1],
        wq[2], bq[2], wo[2], bo[2], wq[3], bq[3], wo[3], bo[3], wg);
    pk_wit<<<768, 256, 0, stream>>>(wi, wiT);

    k1_attn<128><<<dim3(1024, 2), 512, 0, stream>>>(words, wg, flat);
    k1_attn<64> <<<dim3(1024, 2), 512, 0, stream>>>(words, wg, flat);

    k2_mlp<<<512, 512, 0, stream>>>(flat, wiT, bi, wout, bout, (float*)d_out);
}